// Round 7
// baseline (465.931 us; speedup 1.0000x reference)
//
#include <hip/hip_runtime.h>
#include <hip/hip_bf16.h>

// RNN: B=1024, T=512, H=128, +4 autoregressive steps -> out (1024, 516)
// Round 7: 2 waves/SIMD via wave-level group parallelism.
//  R6 diagnosis: 1 wave/SIMD -> all stalls exposed (step pinned ~1263 cyc).
//  R5 diagnosis: G=2 in ONE wave's program order serializes (in-order issue).
//  Fix: 512 thr = 8 waves; waves 0-3 -> batch group 0, waves 4-7 -> group 1.
//  Each wave keeps the R6-optimal structure (MTW=2, off-chain y, 1 barrier).
//  32 blocks x 32 rows; SIMDs now interleave two independent chains.

#define BB 1024
#define TT 512
#define HH 128
#define TOUT 516
#define BM 16          // batch rows per group
#define G 2            // groups per block (wave-sets)
#define MTW 2          // 16-row m-tiles per wave (4 waves * 2 * 16 = 128)
#define HSTR 136       // h stride in bf16 (272 B)
#define XSTR 513       // xs stride (dwords)
#define YSTR 517       // ybuf stride (dwords)
#define PQS 20         // pq row stride (dwords): 80 B, 16B-aligned

typedef __attribute__((ext_vector_type(8))) short bf16x8;
typedef __attribute__((ext_vector_type(4))) short short4_t;
typedef __attribute__((ext_vector_type(4))) float f32x4;

__device__ __forceinline__ short f2bs(float f) {
    __hip_bfloat16 h = __float2bfloat16(f);
    return __builtin_bit_cast(short, h);
}
__device__ __forceinline__ float bs2f(short s) {
    __hip_bfloat16 h = __builtin_bit_cast(__hip_bfloat16, s);
    return __bfloat162float(h);
}

__global__ void detect_dtype(const void* w, int* flag) {
    const int lane = threadIdx.x;  // 64 threads
    const __hip_bfloat16* p = (const __hip_bfloat16*)w;
    const float v0 = __bfloat162float(p[lane]);
    const float v1 = __bfloat162float(p[64 + lane]);
    const bool bad = !(fabsf(v0) < 100.0f) || !(fabsf(v1) < 100.0f);
    const unsigned long long m = __ballot(bad);
    if (lane == 0) *flag = (__popcll(m) > 4) ? 1 : 0;  // 1 => data is fp32
}

template <bool F32>
__device__ __forceinline__ float ldg(const void* p, int idx) {
    if (F32) return ((const float*)p)[idx];
    return __bfloat162float(((const __hip_bfloat16*)p)[idx]);
}

// sum of pq row [0..15] (16B-aligned)
__device__ __forceinline__ float red16(const float* pqrow) {
    const f32x4* pr = (const f32x4*)pqrow;
    const f32x4 s = (pr[0] + pr[1]) + (pr[2] + pr[3]);
    return (s[0] + s[1]) + (s[2] + s[3]);
}

template <bool F32>
__device__ void rnn_body(const void* __restrict__ xg, const void* __restrict__ h0,
                         const void* __restrict__ w0, const void* __restrict__ b0,
                         const void* __restrict__ W,  const void* __restrict__ bw,
                         const void* __restrict__ dw, const void* __restrict__ db,
                         void* __restrict__ out,
                         float (*xs)[XSTR], float (*ybuf)[YSTR],
                         __hip_bfloat16 (*hbuf)[2][BM][HSTR], float (*pq)[2][BM][PQS])
{
    const int tid  = threadIdx.x;
    const int lane = tid & 63;
    const int wv   = tid >> 6;        // 0..7
    const int g    = wv >> 2;         // group 0/1 (wave-set)
    const int wg   = wv & 3;          // wave index within group
    const int q    = lane >> 4;       // 0..3
    const int n    = lane & 15;       // batch col within group
    const int row0 = blockIdx.x * (G * BM);

    // stage x (fp32 in LDS): xs[g*BM+rr][t]
    for (int idx = tid; idx < G * BM * TT; idx += 512) {
        const int rg = idx >> 9, t2 = idx & (TT - 1);
        xs[rg][t2] = ldg<F32>(xg, (row0 + rg) * TT + t2);
    }
    // stage h0 as bf16
    for (int idx = tid; idx < G * BM * HH; idx += 512) {
        const int gg = idx >> 11, rr = (idx >> 7) & (BM - 1), ii = idx & (HH - 1);
        hbuf[gg][0][rr][ii] = __float2bfloat16(ldg<F32>(h0, (row0 + gg * BM + rr) * HH + ii));
    }

    // preload W fragments (A-operand: A[m=lane&15][k=q*8+j]), hi/lo split
    // (same W for both groups; tiles indexed by wg)
    bf16x8 wa_hi[MTW][4], wa_lo[MTW][4];
    #pragma unroll
    for (int m2 = 0; m2 < MTW; ++m2) {
        const int ia = (wg * MTW + m2) * 16 + n;           // W row (output unit)
        #pragma unroll
        for (int kf = 0; kf < 4; ++kf) {
            const int kb = kf * 32 + q * 8;
            bf16x8 hi, lo;
            #pragma unroll
            for (int j = 0; j < 8; ++j) {
                const float f = ldg<F32>(W, ia * HH + kb + j);
                const short hs = f2bs(f);
                hi[j] = hs;
                lo[j] = F32 ? f2bs(f - bs2f(hs)) : (short)0;
            }
            wa_hi[m2][kf] = hi;
            wa_lo[m2][kf] = lo;
        }
    }
    // epilogue constants (C-layout rows: i = (wg*MTW+m2)*16 + q*4 + r)
    float bsum[MTW][4], w0v[MTW][4], decv[MTW][4];
    #pragma unroll
    for (int m2 = 0; m2 < MTW; ++m2)
        #pragma unroll
        for (int r = 0; r < 4; ++r) {
            const int ic = (wg * MTW + m2) * 16 + q * 4 + r;
            bsum[m2][r] = ldg<F32>(b0, ic) + ldg<F32>(bw, ic);
            w0v[m2][r]  = ldg<F32>(w0, ic);
            decv[m2][r] = ldg<F32>(dw, ic);
        }
    const float dbv = ldg<F32>(db, 0);

    __syncthreads();

    int cur = 0;
    float xpref = xs[g * BM + n][0];
    #pragma unroll 1
    for (int t = 0; t < TOUT; ++t) {
        const int par  = t & 1;
        const int par1 = (t - 1) & 1;

        // B-fragments first (longest-latency on-chain loads)
        bf16x8 bfrag[4];
        #pragma unroll
        for (int kf = 0; kf < 4; ++kf)
            bfrag[kf] = *(const bf16x8*)&hbuf[g][cur][n][kf * 32 + q * 8];

        // next step's x (consumed next iter -> latency fully hidden)
        float xnext = 0.0f;
        if (t + 1 < TT) xnext = xs[g * BM + n][t + 1];

        // OFF-chain deferred y writer: last wave of each group emits y[t-1]
        if (wg == 3 && q == 0 && t > 0)
            ybuf[g * BM + n][t - 1] = red16(&pq[g][par1][n][0]) + dbv;

        // step input: prefetched x, or tail feedback (on-chain, 5 steps only)
        float xv;
        if (t < TT) xv = xpref;
        else        xv = red16(&pq[g][par1][n][0]) + dbv;

        // MFMA: acc0 init = bias + x*w0 ; two chains (kf halves), hi+lo shared
        f32x4 acc[MTW][2];
        #pragma unroll
        for (int m2 = 0; m2 < MTW; ++m2) {
            #pragma unroll
            for (int r = 0; r < 4; ++r)
                acc[m2][0][r] = fmaf(xv, w0v[m2][r], bsum[m2][r]);
            acc[m2][1] = (f32x4){0.f, 0.f, 0.f, 0.f};
        }
        #pragma unroll
        for (int kf = 0; kf < 4; ++kf) {
            const int hf = kf >> 1;
            #pragma unroll
            for (int m2 = 0; m2 < MTW; ++m2) {
                acc[m2][hf] = __builtin_amdgcn_mfma_f32_16x16x32_bf16(
                    wa_hi[m2][kf], bfrag[kf], acc[m2][hf], 0, 0, 0);
                if (F32)
                    acc[m2][hf] = __builtin_amdgcn_mfma_f32_16x16x32_bf16(
                        wa_lo[m2][kf], bfrag[kf], acc[m2][hf], 0, 0, 0);
            }
        }

        // epilogue: z -> tanh -> pack bf16 -> private decoder partial
        float p = 0.0f;
        #pragma unroll
        for (int m2 = 0; m2 < MTW; ++m2) {
            short4_t pk;
            #pragma unroll
            for (int r = 0; r < 4; ++r) {
                const float z = acc[m2][0][r] + acc[m2][1][r];
                const float e = __expf(z + z);
                const float h = 1.0f - 2.0f * __builtin_amdgcn_rcpf(e + 1.0f);
                p = fmaf(decv[m2][r], h, p);
                pk[r] = f2bs(h);
            }
            *(short4_t*)&hbuf[g][cur ^ 1][n][(wg * MTW + m2) * 16 + q * 4] = pk;
        }
        // every lane writes its own partial: NO on-chain reduction
        pq[g][par][n][wg * 4 + q] = p;

        xpref = xnext;
        __syncthreads();
        cur ^= 1;
    }

    // tail: y[TOUT-1]
    if (wg == 3 && q == 0)
        ybuf[g * BM + n][TOUT - 1] = red16(&pq[g][(TOUT - 1) & 1][n][0]) + dbv;
    __syncthreads();

    // flush outputs (coalesced over t)
    for (int rg = 0; rg < G * BM; ++rg)
        for (int t2 = tid; t2 < TOUT; t2 += 512) {
            const int o = (row0 + rg) * TOUT + t2;
            const float y = ybuf[rg][t2];
            if (F32) ((float*)out)[o] = y;
            else     ((__hip_bfloat16*)out)[o] = __float2bfloat16(y);
        }
}

__global__ __launch_bounds__(512, 2)
void rnn_mfma(const void* __restrict__ xg, const void* __restrict__ h0,
              const void* __restrict__ w0, const void* __restrict__ b0,
              const void* __restrict__ W,  const void* __restrict__ bw,
              const void* __restrict__ dw, const void* __restrict__ db,
              void* __restrict__ out, const int* __restrict__ flag)
{
    __shared__ float xs[G * BM][XSTR];                          // 65.7 KB
    __shared__ float ybuf[G * BM][YSTR];                        // 66.2 KB
    __shared__ __align__(16) __hip_bfloat16 hbuf[G][2][BM][HSTR]; // 17.4 KB
    __shared__ __align__(16) float pq[G][2][BM][PQS];           // 5.1 KB

    const int f = *(volatile const int*)flag;  // block-uniform
    if (f) rnn_body<true >(xg, h0, w0, b0, W, bw, dw, db, out, xs, ybuf, hbuf, pq);
    else   rnn_body<false>(xg, h0, w0, b0, W, bw, dw, db, out, xs, ybuf, hbuf, pq);
}

extern "C" void kernel_launch(void* const* d_in, const int* in_sizes, int n_in,
                              void* d_out, int out_size, void* d_ws, size_t ws_size,
                              hipStream_t stream) {
    int* flag = (int*)d_ws;
    detect_dtype<<<1, 64, 0, stream>>>(d_in[4], flag);  // probe fc_w
    rnn_mfma<<<BB / (G * BM), 512, 0, stream>>>(d_in[0], d_in[1], d_in[2], d_in[3],
                                                d_in[4], d_in[5], d_in[6], d_in[7],
                                                d_out, flag);
}

// Round 8
// 316.307 us; speedup vs baseline: 1.4730x; 1.4730x over previous
//
#include <hip/hip_runtime.h>
#include <hip/hip_bf16.h>

// RNN: B=1024, T=512, H=128, +4 autoregressive steps -> out (1024, 516)
// Round 8: instruction-count surgery on the R6 skeleton (64 blk x 4 waves).
//  - decoder dot folded into MFMA: 9th A-tile row0 = dec_w (wave 3) ->
//    y[t-1] = dec.h_old computed by the matrix pipe; p-chain/pq/red16 gone
//    from the 511 main steps (kept only for 5 tail steps + y[515]).
//  - loop split into phases: t=0 | pairs t=1..510 (compile-time cur, no
//    conditionals) | t=511 | tail 512..515 (pq feedback) -> no per-iter
//    predicates/cndmasks/runtime-parity addressing.
//  - W hi/lo bf16 split (fp32-exact W), h bf16 in LDS, 1 barrier/step.

#define BB 1024
#define TT 512
#define HH 128
#define TOUT 516
#define BM 16          // batch rows per block
#define MTW 2          // 16-row m-tiles per wave (4 waves * 2 * 16 = 128)
#define HSTR 136       // h stride in bf16 (272 B)
#define XSTR 513       // xs stride (dwords)
#define YSTR 517       // ybuf stride (dwords)
#define PQS 20         // pq row stride (dwords)

typedef __attribute__((ext_vector_type(8))) short bf16x8;
typedef __attribute__((ext_vector_type(4))) short short4_t;
typedef __attribute__((ext_vector_type(4))) float f32x4;

__device__ __forceinline__ short f2bs(float f) {
    __hip_bfloat16 h = __float2bfloat16(f);
    return __builtin_bit_cast(short, h);
}
__device__ __forceinline__ float bs2f(short s) {
    __hip_bfloat16 h = __builtin_bit_cast(__hip_bfloat16, s);
    return __bfloat162float(h);
}

__global__ void detect_dtype(const void* w, int* flag) {
    const int lane = threadIdx.x;  // 64 threads
    const __hip_bfloat16* p = (const __hip_bfloat16*)w;
    const float v0 = __bfloat162float(p[lane]);
    const float v1 = __bfloat162float(p[64 + lane]);
    const bool bad = !(fabsf(v0) < 100.0f) || !(fabsf(v1) < 100.0f);
    const unsigned long long m = __ballot(bad);
    if (lane == 0) *flag = (__popcll(m) > 4) ? 1 : 0;  // 1 => data is fp32
}

template <bool F32>
__device__ __forceinline__ float ldg(const void* p, int idx) {
    if (F32) return ((const float*)p)[idx];
    return __bfloat162float(((const __hip_bfloat16*)p)[idx]);
}

// sum of pq row [0..15] (16B-aligned)
__device__ __forceinline__ float red16(const float* pqrow) {
    const f32x4* pr = (const f32x4*)pqrow;
    const f32x4 s = (pr[0] + pr[1]) + (pr[2] + pr[3]);
    return (s[0] + s[1]) + (s[2] + s[3]);
}

// One RNN step. T_: timestep; CUR_: h read buffer; WRITEY_: wave3 emits
// y[T_-1] from the dec tile; DOPQ_: lanes write decoder partials to pq;
// READX_: prefetch xs[T_+1]; TAILX_: xv from pq reduce (feedback).
#define STEP(T_, CUR_, WRITEY_, DOPQ_, READX_, TAILX_) do {                     \
    bf16x8 bfrag[4];                                                            \
    _Pragma("unroll")                                                           \
    for (int kf = 0; kf < 4; ++kf)                                              \
        bfrag[kf] = *(const bf16x8*)&hbuf[CUR_][n][kf * 32 + q * 8];            \
    float xnext = 0.0f;                                                         \
    if (READX_) xnext = xs[n][(T_) + 1];                                        \
    float xv;                                                                   \
    if (TAILX_) xv = red16(&pq[((T_) - 1) & 1][n][0]) + dbv;                    \
    else        xv = xpref;                                                     \
    f32x4 acc[MTW][2];                                                          \
    _Pragma("unroll")                                                           \
    for (int m2 = 0; m2 < MTW; ++m2) {                                          \
        _Pragma("unroll")                                                       \
        for (int r = 0; r < 4; ++r)                                             \
            acc[m2][0][r] = fmaf(xv, w0v[m2][r], bsum[m2][r]);                  \
        acc[m2][1] = (f32x4){0.f, 0.f, 0.f, 0.f};                               \
    }                                                                           \
    _Pragma("unroll")                                                           \
    for (int kf = 0; kf < 4; ++kf) {                                            \
        const int hf = kf >> 1;                                                 \
        _Pragma("unroll")                                                       \
        for (int m2 = 0; m2 < MTW; ++m2) {                                      \
            acc[m2][hf] = __builtin_amdgcn_mfma_f32_16x16x32_bf16(              \
                wa_hi[m2][kf], bfrag[kf], acc[m2][hf], 0, 0, 0);                \
            if (F32)                                                            \
                acc[m2][hf] = __builtin_amdgcn_mfma_f32_16x16x32_bf16(          \
                    wa_lo[m2][kf], bfrag[kf], acc[m2][hf], 0, 0, 0);            \
        }                                                                       \
    }                                                                           \
    if (isw3) {  /* dec tile: y[T_-1] = dec . h_old (row 0 of tile 8) */        \
        f32x4 accD[2];                                                          \
        accD[0] = (f32x4){0.f, 0.f, 0.f, 0.f};                                  \
        accD[1] = (f32x4){0.f, 0.f, 0.f, 0.f};                                  \
        _Pragma("unroll")                                                       \
        for (int kf = 0; kf < 4; ++kf) {                                        \
            const int hf = kf >> 1;                                             \
            accD[hf] = __builtin_amdgcn_mfma_f32_16x16x32_bf16(                 \
                wa_dhi[kf], bfrag[kf], accD[hf], 0, 0, 0);                      \
            if (F32)                                                            \
                accD[hf] = __builtin_amdgcn_mfma_f32_16x16x32_bf16(             \
                    wa_dlo[kf], bfrag[kf], accD[hf], 0, 0, 0);                  \
        }                                                                       \
        if (WRITEY_) {                                                          \
            const float yp = accD[0][0] + accD[1][0] + dbv;                     \
            if (q == 0) ybuf[n][(T_) - 1] = yp;                                 \
        }                                                                       \
    }                                                                           \
    float p = 0.0f;                                                             \
    _Pragma("unroll")                                                           \
    for (int m2 = 0; m2 < MTW; ++m2) {                                          \
        short4_t pk;                                                            \
        _Pragma("unroll")                                                       \
        for (int r = 0; r < 4; ++r) {                                           \
            const float z = acc[m2][0][r] + acc[m2][1][r];                      \
            const float e = __expf(z + z);                                      \
            const float h = 1.0f - 2.0f * __builtin_amdgcn_rcpf(e + 1.0f);      \
            if (DOPQ_) p = fmaf(decv[m2][r], h, p);                             \
            pk[r] = f2bs(h);                                                    \
        }                                                                       \
        *(short4_t*)&hbuf[(CUR_) ^ 1][n][(wv * MTW + m2) * 16 + q * 4] = pk;    \
    }                                                                           \
    if (DOPQ_) pq[(T_) & 1][n][wv * 4 + q] = p;                                 \
    if (READX_) xpref = xnext;                                                  \
    __syncthreads();                                                            \
} while (0)

template <bool F32>
__device__ void rnn_body(const void* __restrict__ xg, const void* __restrict__ h0,
                         const void* __restrict__ w0, const void* __restrict__ b0,
                         const void* __restrict__ W,  const void* __restrict__ bw,
                         const void* __restrict__ dw, const void* __restrict__ db,
                         void* __restrict__ out,
                         float (*xs)[XSTR], float (*ybuf)[YSTR],
                         __hip_bfloat16 (*hbuf)[BM][HSTR], float (*pq)[BM][PQS])
{
    const int tid  = threadIdx.x;
    const int lane = tid & 63;
    const int wv   = tid >> 6;        // 0..3
    const int q    = lane >> 4;       // 0..3
    const int n    = lane & 15;       // batch col / A-row-in-tile
    const int row0 = blockIdx.x * BM;
    const bool isw3 = (wv == 3);      // wave-uniform

    // stage x (fp32 in LDS)
    for (int idx = tid; idx < BM * TT; idx += 256) {
        const int rr = idx >> 9, t2 = idx & (TT - 1);
        xs[rr][t2] = ldg<F32>(xg, (row0 + rr) * TT + t2);
    }
    // stage h0 as bf16
    for (int idx = tid; idx < BM * HH; idx += 256) {
        const int rr = idx >> 7, ii = idx & (HH - 1);
        hbuf[0][rr][ii] = __float2bfloat16(ldg<F32>(h0, (row0 + rr) * HH + ii));
    }

    // preload W fragments (A-operand: A[m=lane&15][k=q*8+j]), hi/lo split
    bf16x8 wa_hi[MTW][4], wa_lo[MTW][4];
    #pragma unroll
    for (int m2 = 0; m2 < MTW; ++m2) {
        const int ia = (wv * MTW + m2) * 16 + n;           // W row (output unit)
        #pragma unroll
        for (int kf = 0; kf < 4; ++kf) {
            const int kb = kf * 32 + q * 8;
            bf16x8 hi, lo;
            #pragma unroll
            for (int j = 0; j < 8; ++j) {
                const float f = ldg<F32>(W, ia * HH + kb + j);
                const short hs = f2bs(f);
                hi[j] = hs;
                lo[j] = F32 ? f2bs(f - bs2f(hs)) : (short)0;
            }
            wa_hi[m2][kf] = hi;
            wa_lo[m2][kf] = lo;
        }
    }
    // dec tile (wave 3): A row 0 = dec_w, rows 1..15 = 0
    bf16x8 wa_dhi[4] = {}, wa_dlo[4] = {};
    if (isw3) {
        #pragma unroll
        for (int kf = 0; kf < 4; ++kf) {
            const int kb = kf * 32 + q * 8;
            bf16x8 hi = {}, lo = {};
            if (n == 0) {
                #pragma unroll
                for (int j = 0; j < 8; ++j) {
                    const float f = ldg<F32>(dw, kb + j);
                    const short hs = f2bs(f);
                    hi[j] = hs;
                    lo[j] = F32 ? f2bs(f - bs2f(hs)) : (short)0;
                }
            }
            wa_dhi[kf] = hi;
            wa_dlo[kf] = lo;
        }
    }
    // epilogue constants (C-layout rows: i = (wv*MTW+m2)*16 + q*4 + r)
    float bsum[MTW][4], w0v[MTW][4], decv[MTW][4];
    #pragma unroll
    for (int m2 = 0; m2 < MTW; ++m2)
        #pragma unroll
        for (int r = 0; r < 4; ++r) {
            const int ic = (wv * MTW + m2) * 16 + q * 4 + r;
            bsum[m2][r] = ldg<F32>(b0, ic) + ldg<F32>(bw, ic);
            w0v[m2][r]  = ldg<F32>(w0, ic);
            decv[m2][r] = ldg<F32>(dw, ic);
        }
    const float dbv = ldg<F32>(db, 0);

    __syncthreads();

    float xpref = xs[n][0];

    // t = 0: no y yet, no pq
    STEP(0, 0, false, false, true, false);

    // main: t = 1..510, compile-time cur (odd reads buf1, even reads buf0)
    #pragma unroll 1
    for (int t = 1; t < 511; t += 2) {
        STEP(t,     1, true, false, true, false);
        STEP(t + 1, 0, true, false, true, false);
    }

    // t = 511: last x step; start pq for tail feedback
    STEP(511, 1, true, true, false, false);

    // tail: t = 512..515, xv = y[t-1] via pq reduce
    #pragma unroll 1
    for (int t = 512; t < 516; ++t) {
        STEP(t, t & 1, true, true, false, true);
    }

    // final y[515]
    if (isw3 && q == 0)
        ybuf[n][TOUT - 1] = red16(&pq[(TOUT - 1) & 1][n][0]) + dbv;
    __syncthreads();

    // flush outputs (coalesced over t)
    for (int rr = 0; rr < BM; ++rr)
        for (int t2 = tid; t2 < TOUT; t2 += 256) {
            const int o = (row0 + rr) * TOUT + t2;
            const float y = ybuf[rr][t2];
            if (F32) ((float*)out)[o] = y;
            else     ((__hip_bfloat16*)out)[o] = __float2bfloat16(y);
        }
}

__global__ __launch_bounds__(256, 1)
void rnn_mfma(const void* __restrict__ xg, const void* __restrict__ h0,
              const void* __restrict__ w0, const void* __restrict__ b0,
              const void* __restrict__ W,  const void* __restrict__ bw,
              const void* __restrict__ dw, const void* __restrict__ db,
              void* __restrict__ out, const int* __restrict__ flag)
{
    __shared__ float xs[BM][XSTR];                          // 32.8 KB
    __shared__ float ybuf[BM][YSTR];                        // 33.1 KB
    __shared__ __align__(16) __hip_bfloat16 hbuf[2][BM][HSTR]; // 8.7 KB
    __shared__ __align__(16) float pq[2][BM][PQS];          // 2.6 KB

    const int f = *(volatile const int*)flag;  // block-uniform
    if (f) rnn_body<true >(xg, h0, w0, b0, W, bw, dw, db, out, xs, ybuf, hbuf, pq);
    else   rnn_body<false>(xg, h0, w0, b0, W, bw, dw, db, out, xs, ybuf, hbuf, pq);
}

extern "C" void kernel_launch(void* const* d_in, const int* in_sizes, int n_in,
                              void* d_out, int out_size, void* d_ws, size_t ws_size,
                              hipStream_t stream) {
    int* flag = (int*)d_ws;
    detect_dtype<<<1, 64, 0, stream>>>(d_in[4], flag);  // probe fc_w
    rnn_mfma<<<BB / BM, 256, 0, stream>>>(d_in[0], d_in[1], d_in[2], d_in[3],
                                          d_in[4], d_in[5], d_in[6], d_in[7],
                                          d_out, flag);
}

// Round 9
// 264.772 us; speedup vs baseline: 1.7597x; 1.1946x over previous
//
#include <hip/hip_runtime.h>
#include <hip/hip_bf16.h>

// RNN: B=1024, T=512, H=128, +4 autoregressive steps -> out (1024, 516)
// Round 9: 8 waves/block (MTW=1) -> 2 waves/SIMD of the SAME group.
//  R8 diagnosis: 1 wave/SIMD, step=1198cyc = 480 VALU-issue + 280 MFMA +
//  ~440 exposed stalls. Halve per-wave issue and let 2 waves/SIMD hide each
//  other's barrier/LDS/MFMA latency. Same barrier cadence (one group/block).
//  - bf16 pack via +0x8000 round + v_perm_b32 (was ~6-instr RNE seq each).
//  - dec tile hi-only on wave 7 (y error ~6e-4, off the feedback path).
//  - phase-split loop, off-chain y, 1 barrier/step kept from R8.

#define BB 1024
#define TT 512
#define HH 128
#define TOUT 516
#define BM 16          // batch rows per block
#define NW 8           // waves per block; m-tile per wave = 1 (8*16 = 128)
#define HSTR 136       // h stride in bf16 (272 B)
#define XSTR 513       // xs stride (dwords)
#define YSTR 517       // ybuf stride (dwords)
#define PQS 36         // pq row stride (dwords), 144 B (16B-aligned)

typedef __attribute__((ext_vector_type(8))) short bf16x8;
typedef __attribute__((ext_vector_type(4))) float f32x4;

__device__ __forceinline__ short f2bs(float f) {
    __hip_bfloat16 h = __float2bfloat16(f);
    return __builtin_bit_cast(short, h);
}
__device__ __forceinline__ float bs2f(short s) {
    __hip_bfloat16 h = __builtin_bit_cast(__hip_bfloat16, s);
    return __bfloat162float(h);
}

__global__ void detect_dtype(const void* w, int* flag) {
    const int lane = threadIdx.x;  // 64 threads
    const __hip_bfloat16* p = (const __hip_bfloat16*)w;
    const float v0 = __bfloat162float(p[lane]);
    const float v1 = __bfloat162float(p[64 + lane]);
    const bool bad = !(fabsf(v0) < 100.0f) || !(fabsf(v1) < 100.0f);
    const unsigned long long m = __ballot(bad);
    if (lane == 0) *flag = (__popcll(m) > 4) ? 1 : 0;  // 1 => data is fp32
}

template <bool F32>
__device__ __forceinline__ float ldg(const void* p, int idx) {
    if (F32) return ((const float*)p)[idx];
    return __bfloat162float(((const __hip_bfloat16*)p)[idx]);
}

// sum of pq row [0..31] (16B-aligned)
__device__ __forceinline__ float red32(const float* pqrow) {
    const f32x4* v = (const f32x4*)pqrow;
    const f32x4 s = ((v[0] + v[1]) + (v[2] + v[3])) + ((v[4] + v[5]) + (v[6] + v[7]));
    return (s[0] + s[1]) + (s[2] + s[3]);
}

// pack 2 fp32 -> 1 dword of 2 bf16 (round-half-away; ties-only diff vs RNE)
__device__ __forceinline__ unsigned pkbf(float lo, float hi) {
    const unsigned ulo = __builtin_bit_cast(unsigned, lo) + 0x8000u;
    const unsigned uhi = __builtin_bit_cast(unsigned, hi) + 0x8000u;
    return __builtin_amdgcn_perm(uhi, ulo, 0x07060302u);  // {uhi[31:16], ulo[31:16]}
}

// One RNN step. T_: timestep; CUR_: h read buffer; WRITEY_: wave7 dec tile
// emits y[T_-1]; DOPQ_: lanes write decoder partials to pq (tail);
// READX_: prefetch xs[T_+1]; TAILX_: xv from pq reduce (feedback).
#define STEP(T_, CUR_, WRITEY_, DOPQ_, READX_, TAILX_) do {                     \
    bf16x8 bfrag[4];                                                            \
    _Pragma("unroll")                                                           \
    for (int kf = 0; kf < 4; ++kf)                                              \
        bfrag[kf] = *(const bf16x8*)&hbuf[CUR_][n][kf * 32 + q * 8];            \
    float xnext = 0.0f;                                                         \
    if (READX_) xnext = xs[n][(T_) + 1];                                        \
    float xv;                                                                   \
    if (TAILX_) xv = red32(&pq[((T_) - 1) & 1][n][0]) + dbv;                    \
    else        xv = xpref;                                                     \
    f32x4 acc0, acc1;                                                           \
    _Pragma("unroll")                                                           \
    for (int r = 0; r < 4; ++r) acc0[r] = fmaf(xv, w0v[r], bsum[r]);            \
    acc1 = (f32x4){0.f, 0.f, 0.f, 0.f};                                        \
    acc0 = __builtin_amdgcn_mfma_f32_16x16x32_bf16(wa_hi[0], bfrag[0], acc0, 0, 0, 0); \
    if (F32) acc0 = __builtin_amdgcn_mfma_f32_16x16x32_bf16(wa_lo[0], bfrag[0], acc0, 0, 0, 0); \
    acc0 = __builtin_amdgcn_mfma_f32_16x16x32_bf16(wa_hi[1], bfrag[1], acc0, 0, 0, 0); \
    if (F32) acc0 = __builtin_amdgcn_mfma_f32_16x16x32_bf16(wa_lo[1], bfrag[1], acc0, 0, 0, 0); \
    acc1 = __builtin_amdgcn_mfma_f32_16x16x32_bf16(wa_hi[2], bfrag[2], acc1, 0, 0, 0); \
    if (F32) acc1 = __builtin_amdgcn_mfma_f32_16x16x32_bf16(wa_lo[2], bfrag[2], acc1, 0, 0, 0); \
    acc1 = __builtin_amdgcn_mfma_f32_16x16x32_bf16(wa_hi[3], bfrag[3], acc1, 0, 0, 0); \
    if (F32) acc1 = __builtin_amdgcn_mfma_f32_16x16x32_bf16(wa_lo[3], bfrag[3], acc1, 0, 0, 0); \
    if (isw7 && (WRITEY_)) {  /* dec tile (hi only): y[T_-1] = dec . h_old */   \
        f32x4 aD0 = (f32x4){0.f, 0.f, 0.f, 0.f};                                \
        f32x4 aD1 = (f32x4){0.f, 0.f, 0.f, 0.f};                                \
        aD0 = __builtin_amdgcn_mfma_f32_16x16x32_bf16(wa_dhi[0], bfrag[0], aD0, 0, 0, 0); \
        aD0 = __builtin_amdgcn_mfma_f32_16x16x32_bf16(wa_dhi[1], bfrag[1], aD0, 0, 0, 0); \
        aD1 = __builtin_amdgcn_mfma_f32_16x16x32_bf16(wa_dhi[2], bfrag[2], aD1, 0, 0, 0); \
        aD1 = __builtin_amdgcn_mfma_f32_16x16x32_bf16(wa_dhi[3], bfrag[3], aD1, 0, 0, 0); \
        const float yp = aD0[0] + aD1[0] + dbv;                                 \
        if (q == 0) ybuf[n][(T_) - 1] = yp;                                     \
    }                                                                           \
    float p = 0.0f;                                                             \
    float hv[4];                                                                \
    _Pragma("unroll")                                                           \
    for (int r = 0; r < 4; ++r) {                                               \
        const float z = acc0[r] + acc1[r];                                      \
        const float e = __expf(z + z);                                          \
        const float h = fmaf(-2.0f, __builtin_amdgcn_rcpf(e + 1.0f), 1.0f);     \
        if (DOPQ_) p = fmaf(decv[r], h, p);                                     \
        hv[r] = h;                                                              \
    }                                                                           \
    uint2 pk;                                                                   \
    pk.x = pkbf(hv[0], hv[1]);                                                  \
    pk.y = pkbf(hv[2], hv[3]);                                                  \
    *(uint2*)&hbuf[(CUR_) ^ 1][n][wv * 16 + q * 4] = pk;                        \
    if (DOPQ_) pq[(T_) & 1][n][wv * 4 + q] = p;                                 \
    if (READX_) xpref = xnext;                                                  \
    __syncthreads();                                                            \
} while (0)

template <bool F32>
__device__ void rnn_body(const void* __restrict__ xg, const void* __restrict__ h0,
                         const void* __restrict__ w0, const void* __restrict__ b0,
                         const void* __restrict__ W,  const void* __restrict__ bw,
                         const void* __restrict__ dw, const void* __restrict__ db,
                         void* __restrict__ out,
                         float (*xs)[XSTR], float (*ybuf)[YSTR],
                         __hip_bfloat16 (*hbuf)[BM][HSTR], float (*pq)[BM][PQS])
{
    const int tid  = threadIdx.x;
    const int lane = tid & 63;
    const int wv   = tid >> 6;        // 0..7 (= m-tile index)
    const int q    = lane >> 4;       // 0..3
    const int n    = lane & 15;       // batch col / A-row-in-tile
    const int row0 = blockIdx.x * BM;
    const bool isw7 = (wv == 7);      // wave-uniform

    // stage x (fp32 in LDS)
    for (int idx = tid; idx < BM * TT; idx += 512) {
        const int rr = idx >> 9, t2 = idx & (TT - 1);
        xs[rr][t2] = ldg<F32>(xg, (row0 + rr) * TT + t2);
    }
    // stage h0 as bf16
    for (int idx = tid; idx < BM * HH; idx += 512) {
        const int rr = idx >> 7, ii = idx & (HH - 1);
        hbuf[0][rr][ii] = __float2bfloat16(ldg<F32>(h0, (row0 + rr) * HH + ii));
    }

    // preload W fragments (A-operand: A[m=lane&15][k=q*8+j]), hi/lo split
    bf16x8 wa_hi[4], wa_lo[4];
    {
        const int ia = wv * 16 + n;   // W row (output unit)
        #pragma unroll
        for (int kf = 0; kf < 4; ++kf) {
            const int kb = kf * 32 + q * 8;
            bf16x8 hi, lo;
            #pragma unroll
            for (int j = 0; j < 8; ++j) {
                const float f = ldg<F32>(W, ia * HH + kb + j);
                const short hs = f2bs(f);
                hi[j] = hs;
                lo[j] = F32 ? f2bs(f - bs2f(hs)) : (short)0;
            }
            wa_hi[kf] = hi;
            wa_lo[kf] = lo;
        }
    }
    // dec tile (wave 7, hi only): A row 0 = dec_w, rows 1..15 = 0
    bf16x8 wa_dhi[4] = {};
    if (isw7) {
        #pragma unroll
        for (int kf = 0; kf < 4; ++kf) {
            const int kb = kf * 32 + q * 8;
            bf16x8 hi = {};
            if (n == 0) {
                #pragma unroll
                for (int j = 0; j < 8; ++j) hi[j] = f2bs(ldg<F32>(dw, kb + j));
            }
            wa_dhi[kf] = hi;
        }
    }
    // epilogue constants (C-layout rows: i = wv*16 + q*4 + r)
    float bsum[4], w0v[4], decv[4];
    #pragma unroll
    for (int r = 0; r < 4; ++r) {
        const int ic = wv * 16 + q * 4 + r;
        bsum[r] = ldg<F32>(b0, ic) + ldg<F32>(bw, ic);
        w0v[r]  = ldg<F32>(w0, ic);
        decv[r] = ldg<F32>(dw, ic);
    }
    const float dbv = ldg<F32>(db, 0);

    __syncthreads();

    float xpref = xs[n][0];

    // t = 0: no y yet, no pq
    STEP(0, 0, false, false, true, false);

    // main: t = 1..510, compile-time cur (odd reads buf1, even reads buf0)
    #pragma unroll 1
    for (int t = 1; t < 511; t += 2) {
        STEP(t,     1, true, false, true, false);
        STEP(t + 1, 0, true, false, true, false);
    }

    // t = 511: last x step; start pq for tail feedback
    STEP(511, 1, true, true, false, false);

    // tail: t = 512..515, xv = y[t-1] via pq reduce
    #pragma unroll 1
    for (int t = 512; t < 516; ++t) {
        STEP(t, t & 1, true, true, false, true);
    }

    // final y[515]
    if (isw7 && q == 0)
        ybuf[n][TOUT - 1] = red32(&pq[(TOUT - 1) & 1][n][0]) + dbv;
    __syncthreads();

    // flush outputs (coalesced over t)
    for (int rr = 0; rr < BM; ++rr)
        for (int t2 = tid; t2 < TOUT; t2 += 512) {
            const int o = (row0 + rr) * TOUT + t2;
            const float y = ybuf[rr][t2];
            if (F32) ((float*)out)[o] = y;
            else     ((__hip_bfloat16*)out)[o] = __float2bfloat16(y);
        }
}

__global__ __launch_bounds__(512, 2)
void rnn_mfma(const void* __restrict__ xg, const void* __restrict__ h0,
              const void* __restrict__ w0, const void* __restrict__ b0,
              const void* __restrict__ W,  const void* __restrict__ bw,
              const void* __restrict__ dw, const void* __restrict__ db,
              void* __restrict__ out, const int* __restrict__ flag)
{
    __shared__ float xs[BM][XSTR];                          // 32.8 KB
    __shared__ float ybuf[BM][YSTR];                        // 33.1 KB
    __shared__ __align__(16) __hip_bfloat16 hbuf[2][BM][HSTR]; // 8.7 KB
    __shared__ __align__(16) float pq[2][BM][PQS];          // 4.6 KB

    const int f = *(volatile const int*)flag;  // block-uniform
    if (f) rnn_body<true >(xg, h0, w0, b0, W, bw, dw, db, out, xs, ybuf, hbuf, pq);
    else   rnn_body<false>(xg, h0, w0, b0, W, bw, dw, db, out, xs, ybuf, hbuf, pq);
}

extern "C" void kernel_launch(void* const* d_in, const int* in_sizes, int n_in,
                              void* d_out, int out_size, void* d_ws, size_t ws_size,
                              hipStream_t stream) {
    int* flag = (int*)d_ws;
    detect_dtype<<<1, 64, 0, stream>>>(d_in[4], flag);  // probe fc_w
    rnn_mfma<<<BB / BM, 512, 0, stream>>>(d_in[0], d_in[1], d_in[2], d_in[3],
                                          d_in[4], d_in[5], d_in[6], d_in[7],
                                          d_out, flag);
}